// Round 1
// 107.640 us; speedup vs baseline: 1.1628x; 1.1628x over previous
//
#include <hip/hip_runtime.h>
#include <math.h>

#define NH  16
#define SEQ 256
#define HD  64
#define HID 1024
#define N3  3072

// ws layout (float offsets; bf16 regions hold 2 shorts per float slot)
#define OFF_QB   0        // q  bf16 [H][S][D]
#define OFF_KB   131072   // k  bf16 [H][S][D]
#define OFF_KTB  262144   // kt bf16 [H][D][S]
#define OFF_VTB  393216   // vt bf16 [H][D][S]
#define OFF_CTX  524288   // ctx fp32 [S][HID]

typedef __attribute__((ext_vector_type(8))) short bf16x8;
typedef __attribute__((ext_vector_type(4))) float f32x4;
typedef __attribute__((ext_vector_type(2))) unsigned short us2;
typedef __attribute__((ext_vector_type(4))) unsigned short us4;
typedef __attribute__((ext_vector_type(8))) unsigned short us8;

__device__ __forceinline__ unsigned short f2bf(float x) {
  unsigned u = __builtin_bit_cast(unsigned, x);
  u += 0x7FFF + ((u >> 16) & 1);  // RNE
  return (unsigned short)(u >> 16);
}
__device__ __forceinline__ float bf2f(unsigned short b) {
  return __builtin_bit_cast(float, (unsigned)b << 16);
}

// ---------------- K1: fused QKV GEMM (bf16 MFMA) + scatter -------------------
// R9: BM=32 BN=32 BK=64, grid (96,8) = 768 blocks = exactly 3/CU (balanced,
// 12 waves/CU for latency hiding vs old 1.5 blocks/CU) and half the barriers.
// Same-bx blocks land on one XCD (stride 96 % 8 == 0) -> W cols L2-resident.
__global__ __launch_bounds__(256) void k_qkv(
    const float* __restrict__ A, const float* __restrict__ W,
    const float* __restrict__ bias, float* __restrict__ ws,
    float* __restrict__ out) {
  if (blockIdx.x == 0 && blockIdx.y < 4)
    out[SEQ * HID + blockIdx.y * 256 + threadIdx.x] = 0.f;
  __shared__ __align__(16) unsigned short As[32 * 72];
  __shared__ __align__(16) unsigned short Bs[32 * 72];
  const int tid = threadIdx.x;
  const int w = tid >> 6, lane = tid & 63;
  const int col = lane & 15, quad = lane >> 4;
  const int m0 = blockIdx.y * 32, n0 = blockIdx.x * 32;
  const int am = tid >> 3, ak = (tid & 7) * 8;        // A: 32 rows x 64 k
  const int bn = tid & 31, bkg = (tid >> 5) * 8;      // B: 32 n-cols x 64 k
  const float* Wp = W + n0 + bn;
  float4 a0 = *(const float4*)&A[(m0 + am) * HID + ak];
  float4 a1 = *(const float4*)&A[(m0 + am) * HID + ak + 4];
  float pb[8];
#pragma unroll
  for (int u = 0; u < 8; ++u) pb[u] = Wp[(bkg + u) * N3];
  f32x4 acc = {0.f, 0.f, 0.f, 0.f};
  const int k8 = quad * 8;
  const int mt = w & 1, nt = w >> 1;
  for (int k0 = 0; k0 < HID; k0 += 64) {
    *(us8*)&As[am * 72 + ak] =
        (us8){f2bf(a0.x), f2bf(a0.y), f2bf(a0.z), f2bf(a0.w),
              f2bf(a1.x), f2bf(a1.y), f2bf(a1.z), f2bf(a1.w)};
    us8 bp;
#pragma unroll
    for (int u = 0; u < 8; ++u) bp[u] = f2bf(pb[u]);
    *(us8*)&Bs[bn * 72 + bkg] = bp;
    __syncthreads();
    const int kn = k0 + 64;
    if (kn < HID) {
      a0 = *(const float4*)&A[(m0 + am) * HID + kn + ak];
      a1 = *(const float4*)&A[(m0 + am) * HID + kn + ak + 4];
#pragma unroll
      for (int u = 0; u < 8; ++u) pb[u] = Wp[(kn + bkg + u) * N3];
    }
    const bf16x8 af0 = *(const bf16x8*)&As[(mt * 16 + col) * 72 + k8];
    const bf16x8 af1 = *(const bf16x8*)&As[(mt * 16 + col) * 72 + k8 + 32];
    const bf16x8 bf0 = *(const bf16x8*)&Bs[(nt * 16 + col) * 72 + k8];
    const bf16x8 bf1 = *(const bf16x8*)&Bs[(nt * 16 + col) * 72 + k8 + 32];
    acc = __builtin_amdgcn_mfma_f32_16x16x32_bf16(af0, bf0, acc, 0, 0, 0);
    acc = __builtin_amdgcn_mfma_f32_16x16x32_bf16(af1, bf1, acc, 0, 0, 0);
    __syncthreads();
  }
  unsigned short* qb  = (unsigned short*)(ws + OFF_QB);
  unsigned short* kb  = (unsigned short*)(ws + OFF_KB);
  unsigned short* ktb = (unsigned short*)(ws + OFF_KTB);
  unsigned short* vtb = (unsigned short*)(ws + OFF_VTB);
  const int n = n0 + nt * 16 + col;
  const int h = n / 192;
  const int r2 = n - h * 192;
  const int which = r2 >> 6, d = r2 & 63;
  const float bv = bias[n];
#pragma unroll
  for (int r = 0; r < 4; ++r) {
    const int m = m0 + mt * 16 + quad * 4 + r;
    const unsigned short vb = f2bf(acc[r] + bv);
    if (which == 0) {
      qb[(h * SEQ + m) * HD + d] = vb;
    } else if (which == 1) {
      kb[(h * SEQ + m) * HD + d] = vb;
      ktb[(h * HD + d) * SEQ + m] = vb;
    } else {
      vtb[(h * HD + d) * SEQ + m] = vb;  // vt [h][d][s]
    }
  }
}

// ---------------- K2: MFMA flash attention + fused qk_importance -------------
// (unchanged from R6 except: zero-inits out[0..S*HID) for k_dense's split-K
//  atomic accumulation; stream order makes the zeros visible to k_dense)
__global__ __launch_bounds__(256) void k_attn(
    const float* __restrict__ alibi, float* __restrict__ ws,
    float* __restrict__ out) {
  *(float4*)&out[(blockIdx.x * 256 + threadIdx.x) * 4] =
      (float4){0.f, 0.f, 0.f, 0.f};  // 256 blk * 256 thr * 4 = S*HID exactly
  const int bx = blockIdx.x;
  const int h = bx >> 4, i0 = (bx & 15) * 16;
  const int tid = threadIdx.x, w = tid >> 6, lane = tid & 63;
  const int col = lane & 15, quad = lane >> 4;
  __shared__ __align__(16) unsigned short Albs[3 * 16 * 280];  // 26.9 KB
  __shared__ __align__(16) float plds[16 * 260];               // 16.6 KB
  __shared__ __align__(16) float redm[16][4];
  __shared__ __align__(16) float reds[16][4];
  __shared__ __align__(16) float red4[16][4][4];
  __shared__ __align__(16) float rowsc[16][4];
  const unsigned short* qbh  = (const unsigned short*)(ws + OFF_QB) + h * SEQ * HD;
  const unsigned short* kbh  = (const unsigned short*)(ws + OFF_KB) + h * SEQ * HD;
  const unsigned short* ktbh = (const unsigned short*)(ws + OFF_KTB) + h * HD * SEQ;
  const unsigned short* vtbh = (const unsigned short*)(ws + OFF_VTB) + h * HD * SEQ;
  // ---- QK^T ----
  const bf16x8 a0 = *(const bf16x8*)&qbh[(i0 + col) * HD + quad * 8];
  const bf16x8 a1 = *(const bf16x8*)&qbh[(i0 + col) * HD + quad * 8 + 32];
  f32x4 acc[4] = {{0.f, 0.f, 0.f, 0.f}, {0.f, 0.f, 0.f, 0.f},
                  {0.f, 0.f, 0.f, 0.f}, {0.f, 0.f, 0.f, 0.f}};
#pragma unroll
  for (int t = 0; t < 4; ++t) {
    const int j = w * 64 + t * 16 + col;
    const bf16x8 b0 = *(const bf16x8*)&kbh[j * HD + quad * 8];
    const bf16x8 b1 = *(const bf16x8*)&kbh[j * HD + quad * 8 + 32];
    acc[t] = __builtin_amdgcn_mfma_f32_16x16x32_bf16(a0, b0, acc[t], 0, 0, 0);
    acc[t] = __builtin_amdgcn_mfma_f32_16x16x32_bf16(a1, b1, acc[t], 0, 0, 0);
  }
  // ---- scores, E = exp(base), row max ----
  float c[4][4], eb[4][4];
  float rmax[4] = {-3.0e38f, -3.0e38f, -3.0e38f, -3.0e38f};
#pragma unroll
  for (int t = 0; t < 4; ++t) {
    const int j = w * 64 + t * 16 + col;
    const float al = alibi[h * SEQ + j];
#pragma unroll
    for (int r = 0; r < 4; ++r) {
      const int i = i0 + quad * 4 + r;
      const float s = acc[t][r] * 0.125f;
      const float mv = (j <= i) ? 0.f : -1e9f;
      eb[t][r] = __expf((s + mv) * 0.125f);
      const float cv = al + s + mv;
      c[t][r] = cv;
      rmax[r] = fmaxf(rmax[r], cv);
    }
  }
#pragma unroll
  for (int r = 0; r < 4; ++r)
#pragma unroll
    for (int off = 1; off < 16; off <<= 1)
      rmax[r] = fmaxf(rmax[r], __shfl_xor(rmax[r], off));
  if (col == 0)
#pragma unroll
    for (int r = 0; r < 4; ++r) redm[quad * 4 + r][w] = rmax[r];
  __syncthreads();
  // ---- exp(c - M), row sum ----
  float rsum[4];
#pragma unroll
  for (int r = 0; r < 4; ++r) {
    const float4 m4 = *(const float4*)redm[quad * 4 + r];
    const float M = fmaxf(fmaxf(m4.x, m4.y), fmaxf(m4.z, m4.w));
    float s = 0.f;
#pragma unroll
    for (int t = 0; t < 4; ++t) {
      c[t][r] = __expf(c[t][r] - M);
      s += c[t][r];
    }
#pragma unroll
    for (int off = 1; off < 16; off <<= 1) s += __shfl_xor(s, off);
    rsum[r] = s;
  }
  if (col == 0)
#pragma unroll
    for (int r = 0; r < 4; ++r) reds[quad * 4 + r][w] = rsum[r];
  __syncthreads();
  // ---- normalize p, stage P + {E,E²,Ep}, row scalars ----
#pragma unroll
  for (int r = 0; r < 4; ++r) {
    const float4 s4 = *(const float4*)reds[quad * 4 + r];
    const float inv = __builtin_amdgcn_rcpf((s4.x + s4.y) + (s4.z + s4.w));
    const int il = quad * 4 + r;
    float s0 = 0.f, t0 = 0.f, u0 = 0.f, sp = 0.f;
#pragma unroll
    for (int t = 0; t < 4; ++t) {
      const int j = w * 64 + t * 16 + col;
      const float p = c[t][r] * inv;
      const float E = eb[t][r];
      plds[il * 260 + j] = p;
      Albs[il * 280 + j] = f2bf(E);
      Albs[16 * 280 + il * 280 + j] = f2bf(E * E);
      Albs[2 * 16 * 280 + il * 280 + j] = f2bf(E * p);
      s0 += E;
      t0 = __builtin_fmaf(E, E, t0);
      u0 = __builtin_fmaf(E, p, u0);
      sp = __builtin_fmaf(p, p, sp);
    }
#pragma unroll
    for (int off = 1; off < 16; off <<= 1) {
      s0 += __shfl_xor(s0, off);
      t0 += __shfl_xor(t0, off);
      u0 += __shfl_xor(u0, off);
      sp += __shfl_xor(sp, off);
    }
    if (col == 0) *(float4*)&red4[il][w][0] = (float4){s0, t0, u0, sp};
  }
  __syncthreads();
  if (tid < 64) {
    const int row = tid >> 2, x = tid & 3;
    rowsc[row][x] = (red4[row][0][x] + red4[row][1][x]) +
                    (red4[row][2][x] + red4[row][3][x]);
  }
  __syncthreads();
  // ---- PV: wave w -> d = w*16..w*16+15 ----
  f32x4 o = {0.f, 0.f, 0.f, 0.f};
#pragma unroll
  for (int s = 0; s < 8; ++s) {
    const int kk = quad * 8 + s * 32;
    const float4 pa = *(const float4*)&plds[col * 260 + kk];
    const float4 pc = *(const float4*)&plds[col * 260 + kk + 4];
    const us8 af = {f2bf(pa.x), f2bf(pa.y), f2bf(pa.z), f2bf(pa.w),
                    f2bf(pc.x), f2bf(pc.y), f2bf(pc.z), f2bf(pc.w)};
    const bf16x8 vb = *(const bf16x8*)&vtbh[(w * 16 + col) * SEQ + kk];
    o = __builtin_amdgcn_mfma_f32_16x16x32_bf16(
        __builtin_bit_cast(bf16x8, af), vb, o, 0, 0, 0);
  }
  float* ctx = ws + OFF_CTX;
#pragma unroll
  for (int r = 0; r < 4; ++r)
    ctx[(i0 + quad * 4 + r) * HID + h * HD + w * 16 + col] = o[r];
  // ---- moment matmuls {E,E²,Ep} @ [K | K∘K] ----
  f32x4 m6[3][2] = {{{0.f, 0.f, 0.f, 0.f}, {0.f, 0.f, 0.f, 0.f}},
                    {{0.f, 0.f, 0.f, 0.f}, {0.f, 0.f, 0.f, 0.f}},
                    {{0.f, 0.f, 0.f, 0.f}, {0.f, 0.f, 0.f, 0.f}}};
  const unsigned short* ktrow = ktbh + (w * 16 + col) * SEQ;
#pragma unroll
  for (int s = 0; s < 8; ++s) {
    const int kk = quad * 8 + s * 32;
    const bf16x8 kb8 = *(const bf16x8*)&ktrow[kk];
    us8 kq;
#pragma unroll
    for (int u = 0; u < 8; ++u) {
      const float t = bf2f((unsigned short)kb8[u]);
      kq[u] = f2bf(t * t);
    }
    const bf16x8 k2 = __builtin_bit_cast(bf16x8, kq);
#pragma unroll
    for (int lhs = 0; lhs < 3; ++lhs) {
      const bf16x8 af = *(const bf16x8*)&Albs[lhs * 16 * 280 + col * 280 + kk];
      m6[lhs][0] = __builtin_amdgcn_mfma_f32_16x16x32_bf16(af, kb8, m6[lhs][0], 0, 0, 0);
      m6[lhs][1] = __builtin_amdgcn_mfma_f32_16x16x32_bf16(af, k2, m6[lhs][1], 0, 0, 0);
    }
  }
  // ---- closed-form eval + reduce (2nd-order delta expansion) ----
  const int dg = w * 16 + col;
  float racc = 0.f;
#pragma unroll
  for (int r = 0; r < 4; ++r) {
    const int il = quad * 4 + r;
    const float qc = -0.015625f * bf2f(qbh[(i0 + il) * HD + dg]);
    const float s0 = rowsc[il][0], t0 = rowsc[il][1];
    const float u0 = rowsc[il][2], sp = rowsc[il][3];
    const float S1 = __builtin_fmaf(
        qc, __builtin_fmaf(0.5f * qc, m6[0][1][r], m6[0][0][r]), s0);
    const float S2 = __builtin_fmaf(
        2.f * qc, __builtin_fmaf(qc, m6[1][1][r], m6[1][0][r]), t0);
    const float S3 = __builtin_fmaf(
        qc, __builtin_fmaf(0.5f * qc, m6[2][1][r], m6[2][0][r]), u0);
    const float inv = __builtin_amdgcn_rcpf(S1);
    racc += __builtin_fmaf(__builtin_fmaf(S2, inv, -2.f * S3), inv, sp);
  }
  racc += __shfl_xor(racc, 16);
  racc += __shfl_xor(racc, 32);
  if (lane < 16) atomicAdd(&out[SEQ * HID + h * HD + w * 16 + lane], racc);
}

// ---------------- K3: dense GEMM (bf16 MFMA) + bias + residual ---------------
// R9: split-K x4, BM=16 BN=64 BK=64, grid (16,16,4) = 1024 blocks = 4/CU
// (16 waves/CU vs old 4). fp32 atomicAdd epilogue; k-slab 0 adds bias+resid.
// out[0..S*HID) zero-initialized by k_attn (stream-ordered before us).
__global__ __launch_bounds__(256) void k_dense(
    const float* __restrict__ W, const float* __restrict__ bias,
    const float* __restrict__ resid, float* __restrict__ out,
    const float* __restrict__ ws) {
  __shared__ __align__(16) unsigned short As[16 * 72];
  __shared__ __align__(16) unsigned short Bs[64 * 72];
  const int tid = threadIdx.x;
  const int w = tid >> 6, lane = tid & 63;
  const int col = lane & 15, quad = lane >> 4;
  const int m0 = blockIdx.y * 16, n0 = blockIdx.x * 64;
  const int kb = blockIdx.z * 256;
  const int am = tid >> 4, ak = (tid & 15) * 4;   // A: 16 rows x 64 k
  const int bkg = w * 16;                          // B: 64 n-cols x 64 k
  const float* A = ws + OFF_CTX;
  const float* Wp = W + n0 + lane;
  float4 a0 = *(const float4*)&A[(m0 + am) * HID + kb + ak];
  float pb[16];
#pragma unroll
  for (int u = 0; u < 16; ++u) pb[u] = Wp[(kb + bkg + u) * HID];
  f32x4 acc = {0.f, 0.f, 0.f, 0.f};
  const int k8 = quad * 8;
  for (int k0 = 0; k0 < 256; k0 += 64) {
    *(us4*)&As[am * 72 + ak] =
        (us4){f2bf(a0.x), f2bf(a0.y), f2bf(a0.z), f2bf(a0.w)};
    us8 bp0, bp1;
#pragma unroll
    for (int u = 0; u < 8; ++u) { bp0[u] = f2bf(pb[u]); bp1[u] = f2bf(pb[u + 8]); }
    *(us8*)&Bs[lane * 72 + bkg] = bp0;
    *(us8*)&Bs[lane * 72 + bkg + 8] = bp1;
    __syncthreads();
    const int kn = k0 + 64;
    if (kn < 256) {
      a0 = *(const float4*)&A[(m0 + am) * HID + kb + kn + ak];
#pragma unroll
      for (int u = 0; u < 16; ++u) pb[u] = Wp[(kb + kn + bkg + u) * HID];
    }
    const bf16x8 af0 = *(const bf16x8*)&As[col * 72 + k8];
    const bf16x8 af1 = *(const bf16x8*)&As[col * 72 + k8 + 32];
    const bf16x8 bf0 = *(const bf16x8*)&Bs[(w * 16 + col) * 72 + k8];
    const bf16x8 bf1 = *(const bf16x8*)&Bs[(w * 16 + col) * 72 + k8 + 32];
    acc = __builtin_amdgcn_mfma_f32_16x16x32_bf16(af0, bf0, acc, 0, 0, 0);
    acc = __builtin_amdgcn_mfma_f32_16x16x32_bf16(af1, bf1, acc, 0, 0, 0);
    __syncthreads();
  }
  const int n = n0 + w * 16 + col;
  const bool first = (blockIdx.z == 0);
  const float bv = first ? bias[n] : 0.f;
#pragma unroll
  for (int r = 0; r < 4; ++r) {
    const int m = m0 + quad * 4 + r;
    const float v = acc[r] + (first ? bv + resid[m * HID + n] : 0.f);
    atomicAdd(&out[m * HID + n], v);
  }
}

extern "C" void kernel_launch(void* const* d_in, const int* in_sizes, int n_in,
                              void* d_out, int out_size, void* d_ws,
                              size_t ws_size, hipStream_t stream) {
  const float* hidden   = (const float*)d_in[0];
  const float* residual = (const float*)d_in[1];
  const float* alibi    = (const float*)d_in[2];
  const float* Wqkv     = (const float*)d_in[4];
  const float* bqkv     = (const float*)d_in[5];
  const float* Wd       = (const float*)d_in[6];
  const float* bd       = (const float*)d_in[7];
  float* out = (float*)d_out;
  float* ws  = (float*)d_ws;

  k_qkv<<<dim3(96, 8), 256, 0, stream>>>(hidden, Wqkv, bqkv, ws, out);
  k_attn<<<dim3(256), 256, 0, stream>>>(alibi, ws, out);
  k_dense<<<dim3(16, 16, 4), 256, 0, stream>>>(Wd, bd, residual, out, ws);
}

// Round 2
// 104.881 us; speedup vs baseline: 1.1934x; 1.0263x over previous
//
#include <hip/hip_runtime.h>
#include <math.h>

#define NH  16
#define SEQ 256
#define HD  64
#define HID 1024
#define N3  3072

// ws layout (float offsets; bf16 regions hold 2 shorts per float slot)
#define OFF_QB   0        // q  bf16 [H][S][D]
#define OFF_KB   131072   // k  bf16 [H][S][D]
#define OFF_KTB  262144   // kt bf16 [H][D][S]
#define OFF_VTB  393216   // vt bf16 [H][D][S]
#define OFF_CTX  524288   // ctx bf16 [S][HID]  (R10: was fp32)

typedef __attribute__((ext_vector_type(8))) short bf16x8;
typedef __attribute__((ext_vector_type(4))) float f32x4;
typedef __attribute__((ext_vector_type(2))) unsigned short us2;
typedef __attribute__((ext_vector_type(4))) unsigned short us4;
typedef __attribute__((ext_vector_type(8))) unsigned short us8;
typedef __attribute__((ext_vector_type(4))) unsigned u32x4;

__device__ __forceinline__ unsigned short f2bf(float x) {
  unsigned u = __builtin_bit_cast(unsigned, x);
  u += 0x7FFF + ((u >> 16) & 1);  // RNE
  return (unsigned short)(u >> 16);
}
__device__ __forceinline__ float bf2f(unsigned short b) {
  return __builtin_bit_cast(float, (unsigned)b << 16);
}
// R10: hardware packed bf16 convert (RNE, identical to manual f2bf) —
// 1 VALU op per 2 elements vs 4 ops per element.
__device__ __forceinline__ unsigned f2bf2(float lo, float hi) {
  unsigned r;
  asm("v_cvt_pk_bf16_f32 %0, %1, %2" : "=v"(r) : "v"(lo), "v"(hi));
  return r;  // lo in [15:0], hi in [31:16]
}

// ---------------- K1: fused QKV GEMM (bf16 MFMA) + scatter -------------------
// BM=32 BN=32 BK=64, grid (96,8) = 768 blocks = 3/CU (balanced).
// R10: 2-deep register prefetch (unroll-2, named reg sets) to hide cold-HBM
// W latency; cvt_pk staging (was 16x4 VALU f2bf per step).
__global__ __launch_bounds__(256) void k_qkv(
    const float* __restrict__ A, const float* __restrict__ W,
    const float* __restrict__ bias, float* __restrict__ ws,
    float* __restrict__ out) {
  if (blockIdx.x == 0 && blockIdx.y < 4)
    out[SEQ * HID + blockIdx.y * 256 + threadIdx.x] = 0.f;
  __shared__ __align__(16) unsigned short As[32 * 72];
  __shared__ __align__(16) unsigned short Bs[32 * 72];
  const int tid = threadIdx.x;
  const int w = tid >> 6, lane = tid & 63;
  const int col = lane & 15, quad = lane >> 4;
  const int m0 = blockIdx.y * 32, n0 = blockIdx.x * 32;
  const int am = tid >> 3, ak = (tid & 7) * 8;        // A: 32 rows x 64 k
  const int bn = tid & 31, bkg = (tid >> 5) * 8;      // B: 32 n-cols x 64 k
  const float* Ap = &A[(m0 + am) * HID + ak];
  const float* Wp = W + n0 + bn;
  // prologue: preload steps 0 (set A) and 1 (set B)
  float4 a0 = *(const float4*)&Ap[0];
  float4 a1 = *(const float4*)&Ap[4];
  float pa[8];
#pragma unroll
  for (int u = 0; u < 8; ++u) pa[u] = Wp[(bkg + u) * N3];
  float4 c0 = *(const float4*)&Ap[64];
  float4 c1 = *(const float4*)&Ap[68];
  float pc[8];
#pragma unroll
  for (int u = 0; u < 8; ++u) pc[u] = Wp[(64 + bkg + u) * N3];
  f32x4 acc = {0.f, 0.f, 0.f, 0.f};
  const int k8 = quad * 8;
  const int mt = w & 1, nt = w >> 1;
  for (int k0 = 0; k0 < HID; k0 += 128) {
    // ---- sub-step A: K-tile k0 (reg set A), prefetch k0+128 ----
    *(u32x4*)&As[am * 72 + ak] =
        (u32x4){f2bf2(a0.x, a0.y), f2bf2(a0.z, a0.w),
                f2bf2(a1.x, a1.y), f2bf2(a1.z, a1.w)};
    *(u32x4*)&Bs[bn * 72 + bkg] =
        (u32x4){f2bf2(pa[0], pa[1]), f2bf2(pa[2], pa[3]),
                f2bf2(pa[4], pa[5]), f2bf2(pa[6], pa[7])};
    __syncthreads();
    const int ka = k0 + 128;
    if (ka < HID) {
      a0 = *(const float4*)&Ap[ka];
      a1 = *(const float4*)&Ap[ka + 4];
#pragma unroll
      for (int u = 0; u < 8; ++u) pa[u] = Wp[(ka + bkg + u) * N3];
    }
    {
      const bf16x8 af0 = *(const bf16x8*)&As[(mt * 16 + col) * 72 + k8];
      const bf16x8 af1 = *(const bf16x8*)&As[(mt * 16 + col) * 72 + k8 + 32];
      const bf16x8 bf0 = *(const bf16x8*)&Bs[(nt * 16 + col) * 72 + k8];
      const bf16x8 bf1 = *(const bf16x8*)&Bs[(nt * 16 + col) * 72 + k8 + 32];
      acc = __builtin_amdgcn_mfma_f32_16x16x32_bf16(af0, bf0, acc, 0, 0, 0);
      acc = __builtin_amdgcn_mfma_f32_16x16x32_bf16(af1, bf1, acc, 0, 0, 0);
    }
    __syncthreads();
    // ---- sub-step B: K-tile k0+64 (reg set B), prefetch k0+192 ----
    *(u32x4*)&As[am * 72 + ak] =
        (u32x4){f2bf2(c0.x, c0.y), f2bf2(c0.z, c0.w),
                f2bf2(c1.x, c1.y), f2bf2(c1.z, c1.w)};
    *(u32x4*)&Bs[bn * 72 + bkg] =
        (u32x4){f2bf2(pc[0], pc[1]), f2bf2(pc[2], pc[3]),
                f2bf2(pc[4], pc[5]), f2bf2(pc[6], pc[7])};
    __syncthreads();
    const int kb2 = k0 + 192;
    if (kb2 < HID) {
      c0 = *(const float4*)&Ap[kb2];
      c1 = *(const float4*)&Ap[kb2 + 4];
#pragma unroll
      for (int u = 0; u < 8; ++u) pc[u] = Wp[(kb2 + bkg + u) * N3];
    }
    {
      const bf16x8 af0 = *(const bf16x8*)&As[(mt * 16 + col) * 72 + k8];
      const bf16x8 af1 = *(const bf16x8*)&As[(mt * 16 + col) * 72 + k8 + 32];
      const bf16x8 bf0 = *(const bf16x8*)&Bs[(nt * 16 + col) * 72 + k8];
      const bf16x8 bf1 = *(const bf16x8*)&Bs[(nt * 16 + col) * 72 + k8 + 32];
      acc = __builtin_amdgcn_mfma_f32_16x16x32_bf16(af0, bf0, acc, 0, 0, 0);
      acc = __builtin_amdgcn_mfma_f32_16x16x32_bf16(af1, bf1, acc, 0, 0, 0);
    }
    __syncthreads();
  }
  unsigned short* qb  = (unsigned short*)(ws + OFF_QB);
  unsigned short* kb  = (unsigned short*)(ws + OFF_KB);
  unsigned short* ktb = (unsigned short*)(ws + OFF_KTB);
  unsigned short* vtb = (unsigned short*)(ws + OFF_VTB);
  const int n = n0 + nt * 16 + col;
  const int h = n / 192;
  const int r2 = n - h * 192;
  const int which = r2 >> 6, d = r2 & 63;
  const float bv = bias[n];
  const unsigned v01 = f2bf2(acc[0] + bv, acc[1] + bv);
  const unsigned v23 = f2bf2(acc[2] + bv, acc[3] + bv);
  const unsigned short vbr[4] = {
      (unsigned short)v01, (unsigned short)(v01 >> 16),
      (unsigned short)v23, (unsigned short)(v23 >> 16)};
#pragma unroll
  for (int r = 0; r < 4; ++r) {
    const int m = m0 + mt * 16 + quad * 4 + r;
    const unsigned short vb = vbr[r];
    if (which == 0) {
      qb[(h * SEQ + m) * HD + d] = vb;
    } else if (which == 1) {
      kb[(h * SEQ + m) * HD + d] = vb;
      ktb[(h * HD + d) * SEQ + m] = vb;
    } else {
      vtb[(h * HD + d) * SEQ + m] = vb;  // vt [h][d][s]
    }
  }
}

// ---------------- K2: MFMA flash attention + fused qk_importance -------------
// R10: plds holds P as bf16 (PV reads bf16x8 directly, no re-convert);
// all staging converts via cvt_pk; ctx written as bf16.
__global__ __launch_bounds__(256) void k_attn(
    const float* __restrict__ alibi, float* __restrict__ ws,
    float* __restrict__ out) {
  *(float4*)&out[(blockIdx.x * 256 + threadIdx.x) * 4] =
      (float4){0.f, 0.f, 0.f, 0.f};  // 256 blk * 256 thr * 4 = S*HID exactly
  const int bx = blockIdx.x;
  const int h = bx >> 4, i0 = (bx & 15) * 16;
  const int tid = threadIdx.x, w = tid >> 6, lane = tid & 63;
  const int col = lane & 15, quad = lane >> 4;
  __shared__ __align__(16) unsigned short Albs[3 * 16 * 280];  // 26.3 KB
  __shared__ __align__(16) unsigned short plds[16 * 272];      // 8.7 KB (bf16 P)
  __shared__ __align__(16) float redm[16][4];
  __shared__ __align__(16) float reds[16][4];
  __shared__ __align__(16) float red4[16][4][4];
  __shared__ __align__(16) float rowsc[16][4];
  const unsigned short* qbh  = (const unsigned short*)(ws + OFF_QB) + h * SEQ * HD;
  const unsigned short* kbh  = (const unsigned short*)(ws + OFF_KB) + h * SEQ * HD;
  const unsigned short* ktbh = (const unsigned short*)(ws + OFF_KTB) + h * HD * SEQ;
  const unsigned short* vtbh = (const unsigned short*)(ws + OFF_VTB) + h * HD * SEQ;
  // ---- QK^T ----
  const bf16x8 a0 = *(const bf16x8*)&qbh[(i0 + col) * HD + quad * 8];
  const bf16x8 a1 = *(const bf16x8*)&qbh[(i0 + col) * HD + quad * 8 + 32];
  f32x4 acc[4] = {{0.f, 0.f, 0.f, 0.f}, {0.f, 0.f, 0.f, 0.f},
                  {0.f, 0.f, 0.f, 0.f}, {0.f, 0.f, 0.f, 0.f}};
#pragma unroll
  for (int t = 0; t < 4; ++t) {
    const int j = w * 64 + t * 16 + col;
    const bf16x8 b0 = *(const bf16x8*)&kbh[j * HD + quad * 8];
    const bf16x8 b1 = *(const bf16x8*)&kbh[j * HD + quad * 8 + 32];
    acc[t] = __builtin_amdgcn_mfma_f32_16x16x32_bf16(a0, b0, acc[t], 0, 0, 0);
    acc[t] = __builtin_amdgcn_mfma_f32_16x16x32_bf16(a1, b1, acc[t], 0, 0, 0);
  }
  // ---- scores, E = exp(base), row max ----
  float c[4][4], eb[4][4];
  float rmax[4] = {-3.0e38f, -3.0e38f, -3.0e38f, -3.0e38f};
#pragma unroll
  for (int t = 0; t < 4; ++t) {
    const int j = w * 64 + t * 16 + col;
    const float al = alibi[h * SEQ + j];
#pragma unroll
    for (int r = 0; r < 4; ++r) {
      const int i = i0 + quad * 4 + r;
      const float s = acc[t][r] * 0.125f;
      const float mv = (j <= i) ? 0.f : -1e9f;
      eb[t][r] = __expf((s + mv) * 0.125f);
      const float cv = al + s + mv;
      c[t][r] = cv;
      rmax[r] = fmaxf(rmax[r], cv);
    }
  }
#pragma unroll
  for (int r = 0; r < 4; ++r)
#pragma unroll
    for (int off = 1; off < 16; off <<= 1)
      rmax[r] = fmaxf(rmax[r], __shfl_xor(rmax[r], off));
  if (col == 0)
#pragma unroll
    for (int r = 0; r < 4; ++r) redm[quad * 4 + r][w] = rmax[r];
  __syncthreads();
  // ---- exp(c - M), row sum ----
  float rsum[4];
#pragma unroll
  for (int r = 0; r < 4; ++r) {
    const float4 m4 = *(const float4*)redm[quad * 4 + r];
    const float M = fmaxf(fmaxf(m4.x, m4.y), fmaxf(m4.z, m4.w));
    float s = 0.f;
#pragma unroll
    for (int t = 0; t < 4; ++t) {
      c[t][r] = __expf(c[t][r] - M);
      s += c[t][r];
    }
#pragma unroll
    for (int off = 1; off < 16; off <<= 1) s += __shfl_xor(s, off);
    rsum[r] = s;
  }
  if (col == 0)
#pragma unroll
    for (int r = 0; r < 4; ++r) reds[quad * 4 + r][w] = rsum[r];
  __syncthreads();
  // ---- normalize p, stage P(bf16) + {E,E²,Ep}(bf16), row scalars ----
#pragma unroll
  for (int r = 0; r < 4; ++r) {
    const float4 s4 = *(const float4*)reds[quad * 4 + r];
    const float inv = __builtin_amdgcn_rcpf((s4.x + s4.y) + (s4.z + s4.w));
    const int il = quad * 4 + r;
    float pt[4];
    float s0 = 0.f, t0 = 0.f, u0 = 0.f, sp = 0.f;
#pragma unroll
    for (int t = 0; t < 4; ++t) {
      const float p = c[t][r] * inv;
      const float E = eb[t][r];
      pt[t] = p;
      s0 += E;
      t0 = __builtin_fmaf(E, E, t0);
      u0 = __builtin_fmaf(E, p, u0);
      sp = __builtin_fmaf(p, p, sp);
    }
    const int jb = il * 280 + w * 64 + col;   // Albs base
    const int pb = il * 272 + w * 64 + col;   // plds base
    unsigned x;
    x = f2bf2(eb[0][r], eb[1][r]);
    Albs[jb] = (unsigned short)x; Albs[jb + 16] = (unsigned short)(x >> 16);
    x = f2bf2(eb[2][r], eb[3][r]);
    Albs[jb + 32] = (unsigned short)x; Albs[jb + 48] = (unsigned short)(x >> 16);
    x = f2bf2(eb[0][r] * eb[0][r], eb[1][r] * eb[1][r]);
    Albs[4480 + jb] = (unsigned short)x; Albs[4480 + jb + 16] = (unsigned short)(x >> 16);
    x = f2bf2(eb[2][r] * eb[2][r], eb[3][r] * eb[3][r]);
    Albs[4480 + jb + 32] = (unsigned short)x; Albs[4480 + jb + 48] = (unsigned short)(x >> 16);
    x = f2bf2(eb[0][r] * pt[0], eb[1][r] * pt[1]);
    Albs[8960 + jb] = (unsigned short)x; Albs[8960 + jb + 16] = (unsigned short)(x >> 16);
    x = f2bf2(eb[2][r] * pt[2], eb[3][r] * pt[3]);
    Albs[8960 + jb + 32] = (unsigned short)x; Albs[8960 + jb + 48] = (unsigned short)(x >> 16);
    x = f2bf2(pt[0], pt[1]);
    plds[pb] = (unsigned short)x; plds[pb + 16] = (unsigned short)(x >> 16);
    x = f2bf2(pt[2], pt[3]);
    plds[pb + 32] = (unsigned short)x; plds[pb + 48] = (unsigned short)(x >> 16);
#pragma unroll
    for (int off = 1; off < 16; off <<= 1) {
      s0 += __shfl_xor(s0, off);
      t0 += __shfl_xor(t0, off);
      u0 += __shfl_xor(u0, off);
      sp += __shfl_xor(sp, off);
    }
    if (col == 0) *(float4*)&red4[il][w][0] = (float4){s0, t0, u0, sp};
  }
  __syncthreads();
  if (tid < 64) {
    const int row = tid >> 2, x = tid & 3;
    rowsc[row][x] = (red4[row][0][x] + red4[row][1][x]) +
                    (red4[row][2][x] + red4[row][3][x]);
  }
  __syncthreads();
  // ---- PV: wave w -> d = w*16..w*16+15 (P read as bf16 directly) ----
  f32x4 o = {0.f, 0.f, 0.f, 0.f};
#pragma unroll
  for (int s = 0; s < 8; ++s) {
    const int kk = quad * 8 + s * 32;
    const bf16x8 pa8 = *(const bf16x8*)&plds[col * 272 + kk];
    const bf16x8 vb = *(const bf16x8*)&vtbh[(w * 16 + col) * SEQ + kk];
    o = __builtin_amdgcn_mfma_f32_16x16x32_bf16(pa8, vb, o, 0, 0, 0);
  }
  unsigned short* ctxb = (unsigned short*)(ws + OFF_CTX);
  {
    const unsigned x01 = f2bf2(o[0], o[1]);
    const unsigned x23 = f2bf2(o[2], o[3]);
    const int cb = h * HD + w * 16 + col;
    ctxb[(i0 + quad * 4 + 0) * HID + cb] = (unsigned short)x01;
    ctxb[(i0 + quad * 4 + 1) * HID + cb] = (unsigned short)(x01 >> 16);
    ctxb[(i0 + quad * 4 + 2) * HID + cb] = (unsigned short)x23;
    ctxb[(i0 + quad * 4 + 3) * HID + cb] = (unsigned short)(x23 >> 16);
  }
  // ---- moment matmuls {E,E²,Ep} @ [K | K∘K] ----
  f32x4 m6[3][2] = {{{0.f, 0.f, 0.f, 0.f}, {0.f, 0.f, 0.f, 0.f}},
                    {{0.f, 0.f, 0.f, 0.f}, {0.f, 0.f, 0.f, 0.f}},
                    {{0.f, 0.f, 0.f, 0.f}, {0.f, 0.f, 0.f, 0.f}}};
  const unsigned short* ktrow = ktbh + (w * 16 + col) * SEQ;
#pragma unroll
  for (int s = 0; s < 8; ++s) {
    const int kk = quad * 8 + s * 32;
    const bf16x8 kb8 = *(const bf16x8*)&ktrow[kk];
    u32x4 kq4;
#pragma unroll
    for (int u = 0; u < 4; ++u) {
      const float t0 = bf2f((unsigned short)kb8[2 * u]);
      const float t1 = bf2f((unsigned short)kb8[2 * u + 1]);
      kq4[u] = f2bf2(t0 * t0, t1 * t1);
    }
    const bf16x8 k2 = __builtin_bit_cast(bf16x8, kq4);
#pragma unroll
    for (int lhs = 0; lhs < 3; ++lhs) {
      const bf16x8 af = *(const bf16x8*)&Albs[lhs * 4480 + col * 280 + kk];
      m6[lhs][0] = __builtin_amdgcn_mfma_f32_16x16x32_bf16(af, kb8, m6[lhs][0], 0, 0, 0);
      m6[lhs][1] = __builtin_amdgcn_mfma_f32_16x16x32_bf16(af, k2, m6[lhs][1], 0, 0, 0);
    }
  }
  // ---- closed-form eval + reduce (2nd-order delta expansion) ----
  const int dg = w * 16 + col;
  float racc = 0.f;
#pragma unroll
  for (int r = 0; r < 4; ++r) {
    const int il = quad * 4 + r;
    const float qc = -0.015625f * bf2f(qbh[(i0 + il) * HD + dg]);
    const float s0 = rowsc[il][0], t0 = rowsc[il][1];
    const float u0 = rowsc[il][2], sp = rowsc[il][3];
    const float S1 = __builtin_fmaf(
        qc, __builtin_fmaf(0.5f * qc, m6[0][1][r], m6[0][0][r]), s0);
    const float S2 = __builtin_fmaf(
        2.f * qc, __builtin_fmaf(qc, m6[1][1][r], m6[1][0][r]), t0);
    const float S3 = __builtin_fmaf(
        qc, __builtin_fmaf(0.5f * qc, m6[2][1][r], m6[2][0][r]), u0);
    const float inv = __builtin_amdgcn_rcpf(S1);
    racc += __builtin_fmaf(__builtin_fmaf(S2, inv, -2.f * S3), inv, sp);
  }
  racc += __shfl_xor(racc, 16);
  racc += __shfl_xor(racc, 32);
  if (lane < 16) atomicAdd(&out[SEQ * HID + h * HD + w * 16 + lane], racc);
}

// ---------------- K3: dense GEMM (bf16 MFMA) + bias + residual ---------------
// split-K x4, BM=16 BN=64 BK=64, grid (16,16,4) = 1024 blocks = 4/CU.
// R10: ctx is bf16 (direct LDS store, no A-conversion); 2-deep W prefetch;
// cvt_pk W staging. out[0..S*HID) zero-initialized by k_attn.
__global__ __launch_bounds__(256) void k_dense(
    const float* __restrict__ W, const float* __restrict__ bias,
    const float* __restrict__ resid, float* __restrict__ out,
    const float* __restrict__ ws) {
  __shared__ __align__(16) unsigned short As[16 * 72];
  __shared__ __align__(16) unsigned short Bs[64 * 72];
  const int tid = threadIdx.x;
  const int w = tid >> 6, lane = tid & 63;
  const int col = lane & 15, quad = lane >> 4;
  const int m0 = blockIdx.y * 16, n0 = blockIdx.x * 64;
  const int kb = blockIdx.z * 256;
  const int am = tid >> 4, ak = (tid & 15) * 4;   // A: 16 rows x 64 k (shorts)
  const int bkg = w * 16;                          // B: 64 n-cols x 64 k
  const unsigned short* Ab = (const unsigned short*)(ws + OFF_CTX);
  const unsigned short* Ap = &Ab[(m0 + am) * HID + kb + ak];
  const float* Wp = W + n0 + lane;
  // prologue: preload steps 0 (set A) and 1 (set B)
  us4 aA = *(const us4*)&Ap[0];
  float pA[16];
#pragma unroll
  for (int u = 0; u < 16; ++u) pA[u] = Wp[(kb + bkg + u) * HID];
  us4 aB = *(const us4*)&Ap[64];
  float pB[16];
#pragma unroll
  for (int u = 0; u < 16; ++u) pB[u] = Wp[(kb + 64 + bkg + u) * HID];
  f32x4 acc = {0.f, 0.f, 0.f, 0.f};
  const int k8 = quad * 8;
  for (int k0 = 0; k0 < 256; k0 += 128) {
    // ---- sub-step A: K-tile kb+k0, prefetch kb+k0+128 ----
    *(us4*)&As[am * 72 + ak] = aA;
    *(u32x4*)&Bs[lane * 72 + bkg] =
        (u32x4){f2bf2(pA[0], pA[1]), f2bf2(pA[2], pA[3]),
                f2bf2(pA[4], pA[5]), f2bf2(pA[6], pA[7])};
    *(u32x4*)&Bs[lane * 72 + bkg + 8] =
        (u32x4){f2bf2(pA[8], pA[9]), f2bf2(pA[10], pA[11]),
                f2bf2(pA[12], pA[13]), f2bf2(pA[14], pA[15])};
    __syncthreads();
    const int ka = k0 + 128;
    if (ka < 256) {
      aA = *(const us4*)&Ap[ka];
#pragma unroll
      for (int u = 0; u < 16; ++u) pA[u] = Wp[(kb + ka + bkg + u) * HID];
    }
    {
      const bf16x8 af0 = *(const bf16x8*)&As[col * 72 + k8];
      const bf16x8 af1 = *(const bf16x8*)&As[col * 72 + k8 + 32];
      const bf16x8 bf0 = *(const bf16x8*)&Bs[(w * 16 + col) * 72 + k8];
      const bf16x8 bf1 = *(const bf16x8*)&Bs[(w * 16 + col) * 72 + k8 + 32];
      acc = __builtin_amdgcn_mfma_f32_16x16x32_bf16(af0, bf0, acc, 0, 0, 0);
      acc = __builtin_amdgcn_mfma_f32_16x16x32_bf16(af1, bf1, acc, 0, 0, 0);
    }
    __syncthreads();
    // ---- sub-step B: K-tile kb+k0+64, prefetch kb+k0+192 ----
    *(us4*)&As[am * 72 + ak] = aB;
    *(u32x4*)&Bs[lane * 72 + bkg] =
        (u32x4){f2bf2(pB[0], pB[1]), f2bf2(pB[2], pB[3]),
                f2bf2(pB[4], pB[5]), f2bf2(pB[6], pB[7])};
    *(u32x4*)&Bs[lane * 72 + bkg + 8] =
        (u32x4){f2bf2(pB[8], pB[9]), f2bf2(pB[10], pB[11]),
                f2bf2(pB[12], pB[13]), f2bf2(pB[14], pB[15])};
    __syncthreads();
    const int kb2 = k0 + 192;
    if (kb2 < 256) {
      aB = *(const us4*)&Ap[kb2];
#pragma unroll
      for (int u = 0; u < 16; ++u) pB[u] = Wp[(kb + kb2 + bkg + u) * HID];
    }
    {
      const bf16x8 af0 = *(const bf16x8*)&As[col * 72 + k8];
      const bf16x8 af1 = *(const bf16x8*)&As[col * 72 + k8 + 32];
      const bf16x8 bf0 = *(const bf16x8*)&Bs[(w * 16 + col) * 72 + k8];
      const bf16x8 bf1 = *(const bf16x8*)&Bs[(w * 16 + col) * 72 + k8 + 32];
      acc = __builtin_amdgcn_mfma_f32_16x16x32_bf16(af0, bf0, acc, 0, 0, 0);
      acc = __builtin_amdgcn_mfma_f32_16x16x32_bf16(af1, bf1, acc, 0, 0, 0);
    }
    __syncthreads();
  }
  const int n = n0 + w * 16 + col;
  const bool first = (blockIdx.z == 0);
  const float bv = first ? bias[n] : 0.f;
#pragma unroll
  for (int r = 0; r < 4; ++r) {
    const int m = m0 + quad * 4 + r;
    const float v = acc[r] + (first ? bv + resid[m * HID + n] : 0.f);
    atomicAdd(&out[m * HID + n], v);
  }
}

extern "C" void kernel_launch(void* const* d_in, const int* in_sizes, int n_in,
                              void* d_out, int out_size, void* d_ws,
                              size_t ws_size, hipStream_t stream) {
  const float* hidden   = (const float*)d_in[0];
  const float* residual = (const float*)d_in[1];
  const float* alibi    = (const float*)d_in[2];
  const float* Wqkv     = (const float*)d_in[4];
  const float* bqkv     = (const float*)d_in[5];
  const float* Wd       = (const float*)d_in[6];
  const float* bd       = (const float*)d_in[7];
  float* out = (float*)d_out;
  float* ws  = (float*)d_ws;

  k_qkv<<<dim3(96, 8), 256, 0, stream>>>(hidden, Wqkv, bqkv, ws, out);
  k_attn<<<dim3(256), 256, 0, stream>>>(alibi, ws, out);
  k_dense<<<dim3(16, 16, 4), 256, 0, stream>>>(Wd, bd, residual, out, ws);
}